// Round 2
// baseline (30618.463 us; speedup 1.0000x reference)
//
#include <hip/hip_runtime.h>
#include <stdint.h>

#define B_  64
#define T_  1000
#define DI_ 128
#define DR_ 512
#define DO_ 64

// ---------- bf16 helpers ----------
static __device__ __forceinline__ float bfu(uint16_t u){
  union{uint32_t i; float f;} v; v.i = ((uint32_t)u) << 16; return v.f;
}
static __device__ __forceinline__ float blo(uint32_t u){
  union{uint32_t i; float f;} v; v.i = u << 16; return v.f;
}
static __device__ __forceinline__ float bhi(uint32_t u){
  union{uint32_t i; float f;} v; v.i = u & 0xFFFF0000u; return v.f;
}
static __device__ __forceinline__ uint16_t f2bf(float f){
  union{float f; uint32_t i;} v; v.f = f;
  uint32_t i = v.i;
  return (uint16_t)((i + 0x7FFFu + ((i >> 16) & 1u)) >> 16);   // RNE
}

// ---------- dtype-generic scalar IO ----------
template<int BF16> struct IO;
template<> struct IO<1> {
  static __device__ __forceinline__ float ld(const void* p, size_t i){ return bfu(((const uint16_t*)p)[i]); }
  static __device__ __forceinline__ void  st(void* p, size_t i, float v){ ((uint16_t*)p)[i] = f2bf(v); }
};
template<> struct IO<0> {
  static __device__ __forceinline__ float ld(const void* p, size_t i){ return ((const float*)p)[i]; }
  static __device__ __forceinline__ void  st(void* p, size_t i, float v){ ((float*)p)[i] = v; }
};

static __device__ __forceinline__ float retanh_f(float x){
  if (x <= 0.f) return 0.f;
  float e = __expf(2.f * x);
  return 1.f - 2.f / (e + 1.f);
}

// ---------- dtype detection ----------
// bx is uniform(-0.088, 0.088). If stored as bf16, every uint16 is a small
// bf16 (biased exp <= 124  <=>  |v| < 0.25). If stored as fp32 (little-endian),
// EVEN uint16 indices are random low-mantissa halves: P(one looks small) ~ 0.49,
// P(24 in a row) ~ 3e-8. flag: 1 = bf16, 0 = fp32.
__global__ void detect_dtype(const uint16_t* __restrict__ bx, int* __restrict__ flag){
  if (threadIdx.x == 0 && blockIdx.x == 0) {
    int small = 0;
    for (int i = 0; i < 24; ++i) {
      uint16_t u = bx[2 * i];
      uint16_t e = (u >> 7) & 0xFF;
      small += (e <= 124) ? 1 : 0;
    }
    *flag = (small == 24) ? 1 : 0;
  }
}

// ---------- recurrent scan: one block per batch, thread j owns unit j ----------
template<int BF16>
__global__ __launch_bounds__(DR_)
void rnn_run(const void* __restrict__ inp,   // [B,T,DI]
             const void* __restrict__ br,    // [B,T,DR]
             const void* __restrict__ Wrx,   // [DR,DI]
             const void* __restrict__ bx,    // [DR]
             const void* __restrict__ Wrr,   // [DR,DR]
             const void* __restrict__ r0,    // [DR]
             void* __restrict__ rstore,      // [B,T,DR]
             const int* __restrict__ flag)
{
  if (*flag != BF16) return;                 // wrong-dtype variant: no-op
  const int b = blockIdx.x;
  const int j = threadIdx.x;

  __shared__ __align__(16) float s_r[DR_];   // fp32 state for the matmul
  __shared__ __align__(16) float s_in[DI_];  // current input row (fp32)

  // Wrx row j cached in registers as fp32 (128 VGPRs; 8 waves/block, 2/SIMD -> OK)
  float wrx[DI_];
  #pragma unroll
  for (int k = 0; k < DI_; ++k) wrx[k] = IO<BF16>::ld(Wrx, (size_t)j * DI_ + k);

  const float bxj = IO<BF16>::ld(bx, j);
  float rj = IO<BF16>::ld(r0, j);
  s_r[j] = rj;

  const size_t base_in = (size_t)b * T_ * DI_;
  const size_t base_r  = (size_t)b * T_ * DR_;
  __syncthreads();

  #pragma unroll 1
  for (int t = 0; t < T_; ++t) {
    if (j < DI_) s_in[j] = IO<BF16>::ld(inp, base_in + (size_t)t * DI_ + j);
    __syncthreads();                         // s_in ready; s_r(t-1) published

    float acc = bxj;

    // input drive: dot(input_t, Wrx[j,:])
    #pragma unroll
    for (int k = 0; k < DI_; k += 4) {
      float4 iv = *((const float4*)(s_in + k));
      acc = fmaf(wrx[k + 0], iv.x, acc);
      acc = fmaf(wrx[k + 1], iv.y, acc);
      acc = fmaf(wrx[k + 2], iv.z, acc);
      acc = fmaf(wrx[k + 3], iv.w, acc);
    }

    // recurrent drive: dot(r, Wrr[j,:]) — Wrr row streams from L1/L2
    if constexpr (BF16) {
      const uint4* row = (const uint4*)((const uint16_t*)Wrr + (size_t)j * DR_);
      #pragma unroll 8
      for (int k = 0; k < DR_ / 8; ++k) {    // 64 iters, 8 bf16 each
        uint4 w = row[k];
        const float4* rp = (const float4*)(s_r + k * 8);
        float4 ra = rp[0], rb = rp[1];
        acc = fmaf(blo(w.x), ra.x, acc);
        acc = fmaf(bhi(w.x), ra.y, acc);
        acc = fmaf(blo(w.y), ra.z, acc);
        acc = fmaf(bhi(w.y), ra.w, acc);
        acc = fmaf(blo(w.z), rb.x, acc);
        acc = fmaf(bhi(w.z), rb.y, acc);
        acc = fmaf(blo(w.w), rb.z, acc);
        acc = fmaf(bhi(w.w), rb.w, acc);
      }
    } else {
      const float4* row = (const float4*)((const float*)Wrr + (size_t)j * DR_);
      #pragma unroll 8
      for (int k = 0; k < DR_ / 4; ++k) {    // 128 iters, 4 fp32 each
        float4 w  = row[k];
        float4 rv = *((const float4*)(s_r + k * 4));
        acc = fmaf(w.x, rv.x, acc);
        acc = fmaf(w.y, rv.y, acc);
        acc = fmaf(w.z, rv.z, acc);
        acc = fmaf(w.w, rv.w, acc);
      }
    }

    float f   = retanh_f(acc);
    float brv = IO<BF16>::ld(br, base_r + (size_t)t * DR_ + j);
    rj = rj + 0.1f * (f + brv - rj);         // a = DT/TAU = 0.1

    IO<BF16>::st(rstore, base_r + (size_t)t * DR_ + j, rj);
    __syncthreads();                         // everyone done reading old s_r
    s_r[j] = rj;                             // published by next iter's barrier
  }
}

// ---------- output projection: one wave per (b,t) row, lane = output unit ----------
template<int BF16>
__global__ __launch_bounds__(512)
void ygemm(const void* __restrict__ Wyr,     // [DO,DR]
           const void* __restrict__ by,      // [DO]
           const void* __restrict__ rstore,  // [B*T, DR]
           void* __restrict__ y,             // [B*T, DO]
           const int* __restrict__ flag)
{
  if (*flag != BF16) return;
  const int lane = threadIdx.x & 63;
  const int wave = threadIdx.x >> 6;                  // 0..7
  const int row  = blockIdx.x * 8 + wave;             // grid = 8000 -> rows 0..63999

  float acc = IO<BF16>::ld(by, lane);
  if constexpr (BF16) {
    const uint4* wrow = (const uint4*)((const uint16_t*)Wyr + (size_t)lane * DR_);
    const uint4* rrow = (const uint4*)((const uint16_t*)rstore + (size_t)row * DR_);
    #pragma unroll 8
    for (int k = 0; k < DR_ / 8; ++k) {
      uint4 w = wrow[k], r = rrow[k];
      acc = fmaf(blo(w.x), blo(r.x), acc);
      acc = fmaf(bhi(w.x), bhi(r.x), acc);
      acc = fmaf(blo(w.y), blo(r.y), acc);
      acc = fmaf(bhi(w.y), bhi(r.y), acc);
      acc = fmaf(blo(w.z), blo(r.z), acc);
      acc = fmaf(bhi(w.z), bhi(r.z), acc);
      acc = fmaf(blo(w.w), blo(r.w), acc);
      acc = fmaf(bhi(w.w), bhi(r.w), acc);
    }
  } else {
    const float4* wrow = (const float4*)((const float*)Wyr + (size_t)lane * DR_);
    const float4* rrow = (const float4*)((const float*)rstore + (size_t)row * DR_);
    #pragma unroll 8
    for (int k = 0; k < DR_ / 4; ++k) {
      float4 w = wrow[k], r = rrow[k];
      acc = fmaf(w.x, r.x, acc);
      acc = fmaf(w.y, r.y, acc);
      acc = fmaf(w.z, r.z, acc);
      acc = fmaf(w.w, r.w, acc);
    }
  }
  IO<BF16>::st(y, (size_t)row * DO_ + lane, acc);
}

extern "C" void kernel_launch(void* const* d_in, const int* in_sizes, int n_in,
                              void* d_out, int out_size, void* d_ws, size_t ws_size,
                              hipStream_t stream) {
  const void* inp = d_in[0];  // input        [B,T,DI]
  const void* brn = d_in[1];  // brneverlearn [B,T,DR]
  const void* Wrx = d_in[2];  // [DR,DI]
  const void* bx  = d_in[3];  // [DR]
  const void* Wrr = d_in[4];  // [DR,DR]
  const void* Wyr = d_in[5];  // [DO,DR]
  const void* by  = d_in[6];  // [DO]
  const void* r0  = d_in[7];  // [DR]

  int* flag = (int*)d_ws;

  // Output buffer layout: y [B,T,DO] then rstore [B,T,DR], dtype per flag.
  // Compute both candidate pointers; each variant uses its own arithmetic.
  uint16_t* y_bf   = (uint16_t*)d_out;
  uint16_t* rs_bf  = y_bf + (size_t)B_ * T_ * DO_;
  float*    y_f    = (float*)d_out;
  float*    rs_f   = y_f + (size_t)B_ * T_ * DO_;

  hipLaunchKernelGGL(detect_dtype, dim3(1), dim3(64), 0, stream,
                     (const uint16_t*)bx, flag);

  hipLaunchKernelGGL((rnn_run<1>), dim3(B_), dim3(DR_), 0, stream,
                     inp, brn, Wrx, bx, Wrr, r0, (void*)rs_bf, flag);
  hipLaunchKernelGGL((rnn_run<0>), dim3(B_), dim3(DR_), 0, stream,
                     inp, brn, Wrx, bx, Wrr, r0, (void*)rs_f, flag);

  hipLaunchKernelGGL((ygemm<1>), dim3((B_ * T_) / 8), dim3(512), 0, stream,
                     Wyr, by, (const void*)rs_bf, (void*)y_bf, flag);
  hipLaunchKernelGGL((ygemm<0>), dim3((B_ * T_) / 8), dim3(512), 0, stream,
                     Wyr, by, (const void*)rs_f, (void*)y_f, flag);
}

// Round 3
// 10495.706 us; speedup vs baseline: 2.9172x; 2.9172x over previous
//
#include <hip/hip_runtime.h>
#include <stdint.h>

#define B_  64
#define T_  1000
#define DI_ 128
#define DR_ 512
#define DO_ 64

// ---------- bf16 helpers ----------
static __device__ __forceinline__ float bfu(uint16_t u){
  union{uint32_t i; float f;} v; v.i = ((uint32_t)u) << 16; return v.f;
}
static __device__ __forceinline__ uint16_t f2bf(float f){
  union{float f; uint32_t i;} v; v.f = f;
  uint32_t i = v.i;
  return (uint16_t)((i + 0x7FFFu + ((i >> 16) & 1u)) >> 16);   // RNE
}

// ---------- dtype-generic scalar IO ----------
template<int BF16> struct IO;
template<> struct IO<1> {
  static __device__ __forceinline__ float ld(const void* p, size_t i){ return bfu(((const uint16_t*)p)[i]); }
  static __device__ __forceinline__ void  st(void* p, size_t i, float v){ ((uint16_t*)p)[i] = f2bf(v); }
};
template<> struct IO<0> {
  static __device__ __forceinline__ float ld(const void* p, size_t i){ return ((const float*)p)[i]; }
  static __device__ __forceinline__ void  st(void* p, size_t i, float v){ ((float*)p)[i] = v; }
};

static __device__ __forceinline__ float retanh_f(float x){
  if (x <= 0.f) return 0.f;
  float e = __expf(2.f * x);
  return 1.f - 2.f / (e + 1.f);
}

// ---------- init: dtype detect + zero sync counters ----------
// bx uniform(-0.088,0.088): as bf16 every uint16 has biased exp <= 124; as fp32
// the even uint16 halves are random mantissa bits (P(24 all small) ~ 3e-8).
__global__ void init_kernel(const uint16_t* __restrict__ bx, int* __restrict__ flag,
                            unsigned* __restrict__ cnt){
  int t = threadIdx.x;
  if (t < B_) cnt[t] = 0u;
  if (t == 0) {
    int small = 0;
    for (int i = 0; i < 24; ++i) {
      uint16_t u = bx[2 * i];
      uint16_t e = (u >> 7) & 0xFF;
      small += (e <= 124) ? 1 : 0;
    }
    *flag = (small == 24) ? 1 : 0;
  }
}

// ---------- recurrent scan ----------
// 256 blocks = 64 batches x 4 unit-slices of 128 rows. blk = s*64 + b so all 4
// slices of batch b share blk%8 == b%8 (same XCD under round-robin dispatch).
// Thread (q, rl): q = tid>>7 (col quarter), rl = tid&127 (local row).
// Wrr slice rows held in VGPRs (128 fp32/thread). r state broadcast via LDS.
// Cross-slice exchange: double-buffered rglob[2][64][512] in d_ws + per-batch
// monotonic arrival counter (release add / acquire poll, agent scope).
template<int BF16>
__global__ __launch_bounds__(512)
void rnn_run(const void* __restrict__ inp,   // [B,T,DI]
             const void* __restrict__ br,    // [B,T,DR]
             const void* __restrict__ Wrx,   // [DR,DI]
             const void* __restrict__ bx,    // [DR]
             const void* __restrict__ Wrr,   // [DR,DR]
             const void* __restrict__ r0,    // [DR]
             void* __restrict__ rstore,      // [B,T,DR]
             const int* __restrict__ flag,
             unsigned* __restrict__ cnt,     // [B]
             float* __restrict__ rglob)      // [2][B][DR]
{
  if (*flag != BF16) return;
  const int blk = blockIdx.x;
  const int b   = blk & 63;
  const int s   = blk >> 6;          // slice 0..3
  const int tid = threadIdx.x;
  const int q   = tid >> 7;          // col quarter 0..3 (wave-uniform)
  const int rl  = tid & 127;         // local row 0..127
  const int row = s * 128 + rl;      // global unit index this thread serves

  __shared__ __align__(16) float s_r[DR_];
  __shared__ __align__(16) float s_in[DI_];
  __shared__ __align__(16) float s_part[DR_];   // [rl*4 + q]

  // ---- weights in registers ----
  float w[128];
  #pragma unroll
  for (int k = 0; k < 128; ++k)
    w[k] = IO<BF16>::ld(Wrr, (size_t)row * DR_ + q * 128 + k);
  float wx[32];
  #pragma unroll
  for (int k = 0; k < 32; ++k)
    wx[k] = IO<BF16>::ld(Wrx, (size_t)row * DI_ + q * 32 + k);

  const float bxj = (q == 0) ? IO<BF16>::ld(bx, row) : 0.f;
  float rj        = (q == 0) ? IO<BF16>::ld(r0, row) : 0.f;

  s_r[tid & 511] = IO<BF16>::ld(r0, tid & 511);     // full r(–1) = r0
  if (tid < DI_) s_in[tid] = IO<BF16>::ld(inp, (size_t)b * T_ * DI_ + tid);

  const size_t base_in = (size_t)b * T_ * DI_;
  const size_t base_r  = (size_t)b * T_ * DR_;
  bool ok = true;                   // only meaningful on tid==0
  __syncthreads();

  #pragma unroll 1
  for (int t = 0; t < T_; ++t) {
    // early issue of br for this thread's row (q0 only; wave-uniform branch)
    float brv = (q == 0) ? IO<BF16>::ld(br, base_r + (size_t)t * DR_ + row) : 0.f;

    // ---- partial dot: cols q*128..q*128+127 of Wrr row, q*32.. of Wrx row ----
    float a0 = 0.f, a1 = 0.f, a2 = 0.f, a3 = 0.f;
    const float* rq = s_r + q * 128;
    #pragma unroll
    for (int k = 0; k < 128; k += 4) {
      float4 rv = *(const float4*)(rq + k);          // wave-uniform -> broadcast
      a0 = fmaf(w[k + 0], rv.x, a0);
      a1 = fmaf(w[k + 1], rv.y, a1);
      a2 = fmaf(w[k + 2], rv.z, a2);
      a3 = fmaf(w[k + 3], rv.w, a3);
    }
    const float* iq = s_in + q * 32;
    #pragma unroll
    for (int k = 0; k < 32; k += 4) {
      float4 iv = *(const float4*)(iq + k);
      a0 = fmaf(wx[k + 0], iv.x, a0);
      a1 = fmaf(wx[k + 1], iv.y, a1);
      a2 = fmaf(wx[k + 2], iv.z, a2);
      a3 = fmaf(wx[k + 3], iv.w, a3);
    }
    s_part[rl * 4 + q] = (a0 + a1) + (a2 + a3);
    __syncthreads();                                  // B1: partials ready

    // ---- pointwise update (q0) | stage next input (q3) ----
    if (q == 0) {
      float4 p  = *(const float4*)(s_part + rl * 4);
      float tot = (p.x + p.y) + (p.z + p.w) + bxj;
      float f   = retanh_f(tot);
      rj = rj + 0.1f * (f + brv - rj);                // a = DT/TAU
      IO<BF16>::st(rstore, base_r + (size_t)t * DR_ + row, rj);
      s_r[row] = rj;
      __hip_atomic_store(&rglob[((size_t)(t & 1) * B_ + b) * DR_ + row], rj,
                         __ATOMIC_RELAXED, __HIP_MEMORY_SCOPE_AGENT);
    } else if (q == 3) {
      if (t + 1 < T_)
        s_in[rl] = IO<BF16>::ld(inp, base_in + (size_t)(t + 1) * DI_ + rl);
    }
    __syncthreads();                                  // B2: own-slice stores drained

    // ---- arrive + wait for the other 3 slices ----
    if (tid == 0) {
      __hip_atomic_fetch_add(&cnt[b], 1u, __ATOMIC_RELEASE, __HIP_MEMORY_SCOPE_AGENT);
      if (ok) {
        const unsigned target = 4u * (unsigned)(t + 1);
        int spins = 50000;
        while (__hip_atomic_load(&cnt[b], __ATOMIC_ACQUIRE, __HIP_MEMORY_SCOPE_AGENT) < target) {
          __builtin_amdgcn_s_sleep(1);
          if (--spins == 0) { ok = false; break; }    // never trips when co-resident
        }
      }
    }
    __syncthreads();                                  // B3: remote slices published

    // ---- pull remote 384 values into s_r ----
    if (tid < 384) {
      int g = tid + ((tid >= s * 128) ? 128 : 0);     // skip own slice
      float v = __hip_atomic_load(&rglob[((size_t)(t & 1) * B_ + b) * DR_ + g],
                                  __ATOMIC_RELAXED, __HIP_MEMORY_SCOPE_AGENT);
      s_r[g] = v;
    }
    __syncthreads();                                  // B4: s_r(t) complete
  }
}

// ---------- output projection: y = rstore @ Wyr^T + by ----------
// 1000 blocks x 256 threads; block handles 64 rows x 64 outs. K chunked by 128:
// rstore tile + Wyr chunk staged in LDS; Wyr fragment pulled into regs per lane;
// rstore read wave-uniform (broadcast).
template<int BF16>
__global__ __launch_bounds__(256)
void ygemm(const void* __restrict__ Wyr,     // [DO,DR]
           const void* __restrict__ by,      // [DO]
           const void* __restrict__ rstore,  // [B*T, DR]
           void* __restrict__ y,             // [B*T, DO]
           const int* __restrict__ flag)
{
  if (*flag != BF16) return;
  const int tid  = threadIdx.x;
  const int wave = tid >> 6;
  const int lane = tid & 63;
  const int base = blockIdx.x * 64;          // first row of this block

  __shared__ __align__(16) float rs_c[64 * 128];        // 32 KB
  __shared__ __align__(16) float wy_c[64 * 132];        // 33.8 KB (pad vs bank hits)

  float acc[16];
  #pragma unroll
  for (int i = 0; i < 16; ++i) acc[i] = 0.f;

  #pragma unroll 1
  for (int kc = 0; kc < 4; ++kc) {
    // stage rstore[base..base+63][kc*128..+127] and Wyr[0..63][kc*128..+127]
    for (int n = tid; n < 8192; n += 256) {
      int r = n >> 7, k = n & 127;
      rs_c[r * 128 + k] = IO<BF16>::ld(rstore, (size_t)(base + r) * DR_ + kc * 128 + k);
    }
    for (int n = tid; n < 8192; n += 256) {
      int o = n >> 7, k = n & 127;
      wy_c[o * 132 + k] = IO<BF16>::ld(Wyr, (size_t)o * DR_ + kc * 128 + k);
    }
    __syncthreads();

    float4 wf[32];
    #pragma unroll
    for (int m = 0; m < 32; ++m)
      wf[m] = *(const float4*)(wy_c + lane * 132 + m * 4);

    #pragma unroll 1
    for (int i = 0; i < 16; ++i) {
      int r = wave * 16 + i;
      float s0 = 0.f, s1 = 0.f, s2 = 0.f, s3 = 0.f;
      #pragma unroll
      for (int m = 0; m < 32; ++m) {
        float4 rv = *(const float4*)(rs_c + r * 128 + m * 4);   // broadcast
        s0 = fmaf(wf[m].x, rv.x, s0);
        s1 = fmaf(wf[m].y, rv.y, s1);
        s2 = fmaf(wf[m].z, rv.z, s2);
        s3 = fmaf(wf[m].w, rv.w, s3);
      }
      acc[i] += (s0 + s1) + (s2 + s3);
    }
    __syncthreads();
  }

  const float byl = IO<BF16>::ld(by, lane);
  #pragma unroll
  for (int i = 0; i < 16; ++i) {
    int r = base + wave * 16 + i;
    IO<BF16>::st(y, (size_t)r * DO_ + lane, acc[i] + byl);
  }
}

extern "C" void kernel_launch(void* const* d_in, const int* in_sizes, int n_in,
                              void* d_out, int out_size, void* d_ws, size_t ws_size,
                              hipStream_t stream) {
  const void* inp = d_in[0];
  const void* brn = d_in[1];
  const void* Wrx = d_in[2];
  const void* bx  = d_in[3];
  const void* Wrr = d_in[4];
  const void* Wyr = d_in[5];
  const void* by  = d_in[6];
  const void* r0  = d_in[7];

  // workspace layout: [0] dtype flag | [256] cnt[64] | [4096] rglob[2][64][512] f32
  char* ws = (char*)d_ws;
  int*      flag  = (int*)ws;
  unsigned* cnt   = (unsigned*)(ws + 256);
  float*    rglob = (float*)(ws + 4096);

  uint16_t* y_bf  = (uint16_t*)d_out;
  uint16_t* rs_bf = y_bf + (size_t)B_ * T_ * DO_;
  float*    y_f   = (float*)d_out;
  float*    rs_f  = y_f + (size_t)B_ * T_ * DO_;

  hipLaunchKernelGGL(init_kernel, dim3(1), dim3(64), 0, stream,
                     (const uint16_t*)bx, flag, cnt);

  hipLaunchKernelGGL((rnn_run<1>), dim3(4 * B_), dim3(512), 0, stream,
                     inp, brn, Wrx, bx, Wrr, r0, (void*)rs_bf, flag, cnt, rglob);
  hipLaunchKernelGGL((rnn_run<0>), dim3(4 * B_), dim3(512), 0, stream,
                     inp, brn, Wrx, bx, Wrr, r0, (void*)rs_f, flag, cnt, rglob);

  hipLaunchKernelGGL((ygemm<1>), dim3((B_ * T_) / 64), dim3(256), 0, stream,
                     Wyr, by, (const void*)rs_bf, (void*)y_bf, flag);
  hipLaunchKernelGGL((ygemm<0>), dim3((B_ * T_) / 64), dim3(256), 0, stream,
                     Wyr, by, (const void*)rs_f, (void*)y_f, flag);
}